// Round 4
// baseline (2692.216 us; speedup 1.0000x reference)
//
#include <hip/hip_runtime.h>

// RoutingCapsules on MI355X (gfx950)
// x: [B=32, Nin=2048, Din=16] f32
// W: [1, Nin=2048, Nout=64, Dout=32, Din=16] f32
// out v: [B=32, Nout=64, Dout=32] f32
//
// 3 fused W-sweeps (u_hat recomputed per pass, never materialized):
//   pass1: c uniform     -> s1 = (1/64) sum_n u_hat        -> v1
//   pass2: logits=u.v1   -> s2                             -> v2
//   pass3: logits=u.(v1+v2)  (b3 = a1+a2)                  -> v3 = out
//
// Round-4 fix: rounds 1-3 all spilled acc because the VGPR allocator targeted
// 8 waves/EU (64-reg budget) regardless of __launch_bounds__ min-occupancy and
// amdgpu_waves_per_eu(4,4) (attribute changed SGPR alloc but not VGPR).
// New lever: the RA's occupancy target DOES account for static LDS
// (getOccupancyWithLocalMemSize). Pad static LDS to 88 KB -> 1 workgroup/CU
// -> 16 waves = 4 waves/EU -> 128-VGPR budget. Live set ~118 fits, no spill.

#define B_   32
#define NIN  2048
#define DIN  16
#define NOUT 64
#define DOUT 32
#define NCH  8
#define TPB  1024
#define PAD_F 17920   // 70 KB dummy LDS; total 16+2+70 = 88 KB -> 1 block/CU

__device__ __forceinline__ void dot2(const float4* __restrict__ xsrow,
    const float4& w0a, const float4& w0b, const float4& w0c, const float4& w0d,
    const float4& w1a, const float4& w1b, const float4& w1c, const float4& w1d,
    float& u0, float& u1)
{
    float4 xv = xsrow[0];
    u0  = w0a.x*xv.x + w0a.y*xv.y + w0a.z*xv.z + w0a.w*xv.w;
    u1  = w1a.x*xv.x + w1a.y*xv.y + w1a.z*xv.z + w1a.w*xv.w;
    xv = xsrow[1];
    u0 += w0b.x*xv.x + w0b.y*xv.y + w0b.z*xv.z + w0b.w*xv.w;
    u1 += w1b.x*xv.x + w1b.y*xv.y + w1b.z*xv.z + w1b.w*xv.w;
    xv = xsrow[2];
    u0 += w0c.x*xv.x + w0c.y*xv.y + w0c.z*xv.z + w0c.w*xv.w;
    u1 += w1c.x*xv.x + w1c.y*xv.y + w1c.z*xv.z + w1c.w*xv.w;
    xv = xsrow[3];
    u0 += w0d.x*xv.x + w0d.y*xv.y + w0d.z*xv.z + w0d.w*xv.w;
    u1 += w1d.x*xv.x + w1d.y*xv.y + w1d.z*xv.z + w1d.w*xv.w;
}

template<int PASS>
__global__ __launch_bounds__(TPB)
__attribute__((amdgpu_waves_per_eu(4, 4)))
void caps_pass(const float* __restrict__ W, const float* __restrict__ x,
               const float* __restrict__ v_in, float* __restrict__ s_out)
{
    const int t    = threadIdx.x;     // 0..1023
    const int o    = t >> 4;          // 0..63   capsule-out index
    const int dg   = t & 15;          // 0..15
    const int d0   = dg << 1;         // 0,2,..,30  (2 consecutive d's per thread)
    const int lane = t & 63;
    const int nbase = blockIdx.x * NCH;

    __shared__ float4 xs[B_][NCH * DIN / 4];   // [b][nn*4+q], 16 KB
    __shared__ float  lg[2][4][NOUT];          // logit exchange, 2 KB
    __shared__ float  pad[PAD_F];              // occupancy limiter: forces 1 WG/CU
    // DCE-proof use of pad (s_out is never null at runtime, unknown at compile)
    if (__builtin_expect((uintptr_t)s_out == 0, 0)) pad[t] = 1.0f;

    // preload the block's x slice once: x[b][nbase..nbase+7][0..15]
    {
        const int b = t >> 5, j = t & 31;      // 32 float4 per b
        xs[b][j] = ((const float4*)x)[(size_t)b * (NIN * DIN / 4) + nbase * (DIN / 4) + j];
    }

    float acc0[B_], acc1[B_];                  // 64 VGPRs, static-indexed
#pragma unroll
    for (int b = 0; b < B_; ++b) { acc0[b] = 0.f; acc1[b] = 0.f; }

    __syncthreads();

    for (int nn = 0; nn < NCH; ++nn) {
        const int n = nbase + nn;
        // W fragment: rows d0, d0+1 of W[n][o] = 32 consecutive floats (held across b)
        const float4* wp = (const float4*)(W + (((size_t)n * NOUT + o) * DOUT + d0) * DIN);
        const float4 w0a = wp[0], w0b = wp[1], w0c = wp[2], w0d = wp[3];
        const float4 w1a = wp[4], w1b = wp[5], w1c = wp[6], w1d = wp[7];

        if (PASS == 1) {
#pragma unroll
            for (int b = 0; b < B_; ++b) {
                float u0, u1;
                dot2(&xs[b][nn * 4], w0a, w0b, w0c, w0d, w1a, w1b, w1c, w1d, u0, u1);
                acc0[b] += u0;
                acc1[b] += u1;
            }
        } else {
#pragma unroll
            for (int g = 0; g < 8; ++g) {       // b-groups of 4 (u-stash = 8 regs)
                float u0r[4], u1r[4];
#pragma unroll
                for (int bb = 0; bb < 4; ++bb) {
                    const int b = g * 4 + bb;
                    float u0, u1;
                    dot2(&xs[b][nn * 4], w0a, w0b, w0c, w0d, w1a, w1b, w1c, w1d, u0, u1);
                    u0r[bb] = u0; u1r[bb] = u1;
                    // logit partial: this thread's 2 d's; v is L2-resident (256 KB)
                    const float2 vv = *(const float2*)&v_in[((size_t)b * NOUT + o) * DOUT + d0];
                    float p = u0 * vv.x + u1 * vv.y;
                    p += __shfl_xor(p, 1);
                    p += __shfl_xor(p, 2);
                    p += __shfl_xor(p, 4);
                    p += __shfl_xor(p, 8);      // full dot over d within 16-lane group
                    if (dg == 0) lg[g & 1][bb][o] = p;
                }
                __syncthreads();
#pragma unroll
                for (int bb = 0; bb < 4; ++bb) {
                    const int b = g * 4 + bb;
                    // softmax over o=64; no max-sub needed (|logit| << 88)
                    float e = __expf(lg[g & 1][bb][lane]);
                    float sm = e;
#pragma unroll
                    for (int m = 1; m < 64; m <<= 1) sm += __shfl_xor(sm, m);
                    const float cw = __shfl(e, o) / sm;
                    acc0[b] += cw * u0r[bb];
                    acc1[b] += cw * u1r[bb];
                }
            }
        }
    }

    const float scale = (PASS == 1) ? (1.0f / 64.0f) : 1.0f;
#pragma unroll
    for (int b = 0; b < B_; ++b) {
        float* dst = &s_out[((size_t)b * NOUT + o) * DOUT + d0];
        atomicAdd(dst,     acc0[b] * scale);
        atomicAdd(dst + 1, acc1[b] * scale);
    }
}

// v = squash(s) per (b,o) row of 32 d; accumulate==1 -> vout += squash(s)
__global__ void squash_k(const float* __restrict__ s, float* __restrict__ vout,
                         int accumulate)
{
    const int idx = blockIdx.x * 256 + threadIdx.x;   // 65536 elements
    const float val = s[idx];
    float sq = val * val;
#pragma unroll
    for (int m = 1; m < 32; m <<= 1) sq += __shfl_xor(sq, m);  // row = 32 lanes
    const float f = sq / ((1.0f + sq) * sqrtf(sq + 1e-8f));
    const float v = val * f;
    if (accumulate) vout[idx] += v;
    else            vout[idx] = v;
}

extern "C" void kernel_launch(void* const* d_in, const int* in_sizes, int n_in,
                              void* d_out, int out_size, void* d_ws, size_t ws_size,
                              hipStream_t stream)
{
    (void)in_sizes; (void)n_in; (void)out_size; (void)ws_size;
    const float* x = (const float*)d_in[0];
    const float* W = (const float*)d_in[1];
    float* out = (float*)d_out;

    float* s  = (float*)d_ws;         // 65536 f32 = 256 KB
    float* vA = s + 65536;            // 65536 f32 = 256 KB (v1, then v1+v2)
    const size_t sbytes = (size_t)65536 * sizeof(float);

    // ---- iter 1: uniform c -> s1 -> v1
    hipMemsetAsync(s, 0, sbytes, stream);
    caps_pass<1><<<dim3(NIN / NCH), dim3(TPB), 0, stream>>>(W, x, nullptr, s);
    squash_k<<<dim3(256), dim3(256), 0, stream>>>(s, vA, 0);      // vA = v1

    // ---- iter 2: logits = u.v1 -> s2 -> v2 ; vA = v1+v2
    hipMemsetAsync(s, 0, sbytes, stream);
    caps_pass<2><<<dim3(NIN / NCH), dim3(TPB), 0, stream>>>(W, x, vA, s);
    squash_k<<<dim3(256), dim3(256), 0, stream>>>(s, vA, 1);      // vA = v1 + v2

    // ---- iter 3: logits = u.(v1+v2) -> s3 -> out = v3
    hipMemsetAsync(s, 0, sbytes, stream);
    caps_pass<2><<<dim3(NIN / NCH), dim3(TPB), 0, stream>>>(W, x, vA, s);
    squash_k<<<dim3(256), dim3(256), 0, stream>>>(s, out, 0);
}

// Round 5
// 872.965 us; speedup vs baseline: 3.0840x; 3.0840x over previous
//
#include <hip/hip_runtime.h>

// RoutingCapsules on MI355X (gfx950)
// x: [B=32, Nin=2048, Din=16] f32
// W: [1, Nin=2048, Nout=64, Dout=32, Din=16] f32
// out v: [B=32, Nout=64, Dout=32] f32
//
// 3 fused W-sweeps (u_hat recomputed per pass, never materialized):
//   pass1: c uniform     -> s1 = (1/64) sum_n u_hat        -> v1
//   pass2: logits=u.v1   -> s2                             -> v2
//   pass3: logits=u.(v1+v2)  (b3 = a1+a2)                  -> v3 = out
//
// Round-5: rounds 1-4 proved the VGPR allocator pins 64 regs regardless of
// __launch_bounds__ / amdgpu_waves_per_eu / LDS-forced occupancy -> the
// ~118-reg live set always spilled (2.7 GB/pass scratch writes). Fix: design
// for 64 regs. Each block owns 8 batches (b-quad): acc 16 regs + W frag 32
// + temps ~ 60-70 peak. PASS2 u-stash lives in LDS (thread-private slots).
// The 4 b-quad siblings share their W chunk via XCD L2 (swizzle puts them on
// the same XCD, adjacent in dispatch).

#define B_   32
#define NIN  2048
#define DIN  16
#define NOUT 64
#define DOUT 32
#define NCH  8
#define TPB  1024
#define BQ   8                                   // batches per block
#define NBLK ((NIN / NCH) * (B_ / BQ))           // 256 chunks * 4 quads = 1024

template<int PASS>
__global__ __launch_bounds__(TPB)
void caps_pass(const float* __restrict__ W, const float* __restrict__ x,
               const float* __restrict__ v_in, float* __restrict__ s_out)
{
    const int t    = threadIdx.x;     // 0..1023
    const int o    = t >> 4;          // 0..63   capsule-out index
    const int dg   = t & 15;          // 0..15
    const int d0   = dg << 1;         // 0,2,..,30  (2 consecutive d's)
    const int lane = t & 63;

    // Swizzle: 4 sibling blocks (same n-chunk, different b-quad) land on the
    // same XCD (bid%8 round-robin assumption) and adjacent in dispatch order,
    // so the shared 1 MB W chunk is HBM-fetched once, L2-hit 3x.
    const int bid   = blockIdx.x;
    const int xcd   = bid & 7;
    const int jj    = bid >> 3;               // 0..127
    const int chunk = xcd * 32 + (jj >> 2);   // 0..255
    const int quad  = jj & 3;                 // 0..3
    const int nbase = chunk * NCH;
    const int bbase = quad * BQ;

    __shared__ float4 xs[BQ][NCH * DIN / 4];  // 4 KB: x[bquad][8 n][16 i]

    if (t < BQ * NCH * DIN / 4) {             // 256 float4
        const int bb = t >> 5;
        const int k  = t & 31;
        xs[bb][k] = ((const float4*)x)[(size_t)(bbase + bb) * (NIN * DIN / 4)
                                       + (size_t)nbase * (DIN / 4) + k];
    }

    float acc0[BQ], acc1[BQ];                 // 16 VGPRs, static-indexed
#pragma unroll
    for (int bb = 0; bb < BQ; ++bb) { acc0[bb] = 0.f; acc1[bb] = 0.f; }

    __syncthreads();

    if (PASS == 1) {
        for (int nn = 0; nn < NCH; ++nn) {
            const float4* wp = (const float4*)(W +
                (((size_t)(nbase + nn) * NOUT + o) * DOUT + d0) * DIN);
            float4 w[8];                      // 32 VGPRs: rows d0,d0+1 of W[n][o]
#pragma unroll
            for (int q = 0; q < 8; ++q) w[q] = wp[q];
#pragma unroll
            for (int bb = 0; bb < BQ; ++bb) {
                const float4* xr = &xs[bb][nn * 4];
                float u0 = 0.f, u1 = 0.f;
#pragma unroll
                for (int q = 0; q < 4; ++q) {
                    const float4 xv = xr[q];
                    u0 += w[q].x*xv.x + w[q].y*xv.y + w[q].z*xv.z + w[q].w*xv.w;
                    u1 += w[4+q].x*xv.x + w[4+q].y*xv.y + w[4+q].z*xv.z + w[4+q].w*xv.w;
                }
                acc0[bb] += u0;
                acc1[bb] += u1;
            }
        }
    } else {
        __shared__ float  lg[2][BQ][NOUT];    // 4 KB, parity double-buffered
        __shared__ float2 ustash[BQ][TPB];    // 64 KB, thread-private slots
        for (int nn = 0; nn < NCH; ++nn) {
            const int par = nn & 1;
            const float4* wp = (const float4*)(W +
                (((size_t)(nbase + nn) * NOUT + o) * DOUT + d0) * DIN);
            float4 w[8];
#pragma unroll
            for (int q = 0; q < 8; ++q) w[q] = wp[q];
#pragma unroll
            for (int bb = 0; bb < BQ; ++bb) {
                const float4* xr = &xs[bb][nn * 4];
                float u0 = 0.f, u1 = 0.f;
#pragma unroll
                for (int q = 0; q < 4; ++q) {
                    const float4 xv = xr[q];
                    u0 += w[q].x*xv.x + w[q].y*xv.y + w[q].z*xv.z + w[q].w*xv.w;
                    u1 += w[4+q].x*xv.x + w[4+q].y*xv.y + w[4+q].z*xv.z + w[4+q].w*xv.w;
                }
                // logit partial over this thread's 2 d's; v is L1/L2-resident
                const float2 vv = ((const float2*)v_in)[
                    (size_t)(bbase + bb) * (NOUT * DOUT / 2) + o * (DOUT / 2) + dg];
                float p = u0 * vv.x + u1 * vv.y;
                p += __shfl_xor(p, 1);
                p += __shfl_xor(p, 2);
                p += __shfl_xor(p, 4);
                p += __shfl_xor(p, 8);        // full dot over d in 16-lane group
                if (dg == 0) lg[par][bb][o] = p;
                ustash[bb][t] = make_float2(u0, u1);   // private slot: no hazard
            }
            __syncthreads();                  // 1 barrier per nn (lg parity-buffered)
#pragma unroll
            for (int bb = 0; bb < BQ; ++bb) {
                // softmax over o=64; no max-sub needed (|logit| << 88)
                float e = __expf(lg[par][bb][lane]);
                float sm = e;
#pragma unroll
                for (int m = 1; m < 64; m <<= 1) sm += __shfl_xor(sm, m);
                const float cw = __shfl(e, o) / sm;
                const float2 u = ustash[bb][t];
                acc0[bb] += cw * u.x;
                acc1[bb] += cw * u.y;
            }
        }
    }

    const float scale = (PASS == 1) ? (1.0f / 64.0f) : 1.0f;
#pragma unroll
    for (int bb = 0; bb < BQ; ++bb) {
        float* dst = &s_out[((size_t)(bbase + bb) * NOUT + o) * DOUT + d0];
        atomicAdd(dst,     acc0[bb] * scale);
        atomicAdd(dst + 1, acc1[bb] * scale);
    }
}

// v = squash(s) per (b,o) row of 32 d; accumulate==1 -> vout += squash(s)
__global__ void squash_k(const float* __restrict__ s, float* __restrict__ vout,
                         int accumulate)
{
    const int idx = blockIdx.x * 256 + threadIdx.x;   // 65536 elements
    const float val = s[idx];
    float sq = val * val;
#pragma unroll
    for (int m = 1; m < 32; m <<= 1) sq += __shfl_xor(sq, m);  // row = 32 lanes
    const float f = sq / ((1.0f + sq) * sqrtf(sq + 1e-8f));
    const float v = val * f;
    if (accumulate) vout[idx] += v;
    else            vout[idx] = v;
}

extern "C" void kernel_launch(void* const* d_in, const int* in_sizes, int n_in,
                              void* d_out, int out_size, void* d_ws, size_t ws_size,
                              hipStream_t stream)
{
    (void)in_sizes; (void)n_in; (void)out_size; (void)ws_size;
    const float* x = (const float*)d_in[0];
    const float* W = (const float*)d_in[1];
    float* out = (float*)d_out;

    float* s  = (float*)d_ws;         // 65536 f32 = 256 KB
    float* vA = s + 65536;            // 65536 f32 = 256 KB (v1, then v1+v2)
    const size_t sbytes = (size_t)65536 * sizeof(float);

    // ---- iter 1: uniform c -> s1 -> v1
    hipMemsetAsync(s, 0, sbytes, stream);
    caps_pass<1><<<dim3(NBLK), dim3(TPB), 0, stream>>>(W, x, nullptr, s);
    squash_k<<<dim3(256), dim3(256), 0, stream>>>(s, vA, 0);      // vA = v1

    // ---- iter 2: logits = u.v1 -> s2 -> v2 ; vA = v1+v2
    hipMemsetAsync(s, 0, sbytes, stream);
    caps_pass<2><<<dim3(NBLK), dim3(TPB), 0, stream>>>(W, x, vA, s);
    squash_k<<<dim3(256), dim3(256), 0, stream>>>(s, vA, 1);      // vA = v1 + v2

    // ---- iter 3: logits = u.(v1+v2) -> s3 -> out = v3
    hipMemsetAsync(s, 0, sbytes, stream);
    caps_pass<2><<<dim3(NBLK), dim3(TPB), 0, stream>>>(W, x, vA, s);
    squash_k<<<dim3(256), dim3(256), 0, stream>>>(s, out, 0);
}

// Round 6
// 665.763 us; speedup vs baseline: 4.0438x; 1.3112x over previous
//
#include <hip/hip_runtime.h>

// RoutingCapsules on MI355X (gfx950)
// x: [B=32, Nin=2048, Din=16] f32
// W: [1, Nin=2048, Nout=64, Dout=32, Din=16] f32
// out v: [B=32, Nout=64, Dout=32] f32
//
// 3 fused W-sweeps (u_hat recomputed, never materialized):
//   pass1: c uniform     -> s1 = (1/64) sum_n u_hat        -> v1
//   pass2: logits=u.v1   -> s2                             -> v2
//   pass3: logits=u.(v1+v2)  (b3 = a1+a2)                  -> v3 = out
//
// Round-6: round 5's profile was pure atomic-RMW traffic (FETCH+WRITE ==
// 16.8M atomics x 16B; W was L3-served). Cross-XCD device-scope atomics
// resolve at the fabric -> write-through RMW, ~50 G/s -> that WAS the 338 us.
// Fix: blocks stream 64 KB partials to ws (coalesced stores), fused
// reduce+squash kernel sums 128 chunk-partials. Atomic path kept as runtime
// fallback if ws_size < 33 MB (deterministic branch).

#define B_   32
#define NIN  2048
#define DIN  16
#define NOUT 64
#define DOUT 32
#define BQ   8                          // batches per block
#define NCHB 16                         // n per block
#define CG   (NIN / NCHB)               // 128 chunk-groups
#define NBLK (CG * (B_ / BQ))           // 128 * 4 = 512 blocks
#define TPB  1024
#define PART_PER_BLK (BQ * NOUT * DOUT / 2)   // 8192 float2 per block (64 KB)

template<int PASS, bool ATOMIC>
__global__ __launch_bounds__(TPB)
void caps_pass(const float* __restrict__ W, const float* __restrict__ x,
               const float* __restrict__ v_in, float* __restrict__ s_out,
               float2* __restrict__ part)
{
    const int t    = threadIdx.x;     // 0..1023
    const int o    = t >> 4;          // 0..63   capsule-out index
    const int dg   = t & 15;          // 0..15
    const int d0   = dg << 1;         // 0,2,..,30
    const int lane = t & 63;

    // Swizzle: the 4 quad-siblings (same n-chunk, different b-quad) land on
    // the same XCD adjacent in dispatch -> shared 2 MB W chunk is L2-hit 3x.
    const int bid  = blockIdx.x;
    const int xcd  = bid & 7;
    const int j    = bid >> 3;                // 0..63
    const int cg   = xcd * (CG / 8) + (j >> 2);   // 0..127
    const int quad = j & 3;                   // 0..3
    const int nbase = cg * NCHB;
    const int bbase = quad * BQ;

    __shared__ float4 xs[BQ][NCHB * DIN / 4];   // 8 KB: x[bquad][16 n][16 i]

    if (t < BQ * NCHB * DIN / 4) {              // 512 float4
        const int bb = t >> 6;
        const int k  = t & 63;
        xs[bb][k] = ((const float4*)x)[(size_t)(bbase + bb) * (NIN * DIN / 4)
                                       + (size_t)nbase * (DIN / 4) + k];
    }

    float acc0[BQ], acc1[BQ];                   // 16 VGPRs
#pragma unroll
    for (int bb = 0; bb < BQ; ++bb) { acc0[bb] = 0.f; acc1[bb] = 0.f; }

    __syncthreads();

    if constexpr (PASS == 1) {
        for (int nn = 0; nn < NCHB; ++nn) {
            const float4* wp = (const float4*)(W +
                (((size_t)(nbase + nn) * NOUT + o) * DOUT + d0) * DIN);
            float4 w[8];                        // 32 VGPRs
#pragma unroll
            for (int q = 0; q < 8; ++q) w[q] = wp[q];
#pragma unroll
            for (int bb = 0; bb < BQ; ++bb) {
                const float4* xr = &xs[bb][nn * 4];
                float u0 = 0.f, u1 = 0.f;
#pragma unroll
                for (int q = 0; q < 4; ++q) {
                    const float4 xv = xr[q];
                    u0 += w[q].x*xv.x + w[q].y*xv.y + w[q].z*xv.z + w[q].w*xv.w;
                    u1 += w[4+q].x*xv.x + w[4+q].y*xv.y + w[4+q].z*xv.z + w[4+q].w*xv.w;
                }
                acc0[bb] += u0;
                acc1[bb] += u1;
            }
        }
    } else {
        __shared__ float  lg[2][BQ][NOUT];      // 4 KB, parity double-buffered
        __shared__ float2 ustash[BQ][TPB];      // 64 KB, thread-private slots
        for (int nn = 0; nn < NCHB; ++nn) {
            const int par = nn & 1;
            const float4* wp = (const float4*)(W +
                (((size_t)(nbase + nn) * NOUT + o) * DOUT + d0) * DIN);
            float4 w[8];
#pragma unroll
            for (int q = 0; q < 8; ++q) w[q] = wp[q];
#pragma unroll
            for (int bb = 0; bb < BQ; ++bb) {
                const float4* xr = &xs[bb][nn * 4];
                float u0 = 0.f, u1 = 0.f;
#pragma unroll
                for (int q = 0; q < 4; ++q) {
                    const float4 xv = xr[q];
                    u0 += w[q].x*xv.x + w[q].y*xv.y + w[q].z*xv.z + w[q].w*xv.w;
                    u1 += w[4+q].x*xv.x + w[4+q].y*xv.y + w[4+q].z*xv.z + w[4+q].w*xv.w;
                }
                // logit partial over this thread's 2 d's; v is L1/L2-resident
                const float2 vv = ((const float2*)v_in)[
                    (size_t)(bbase + bb) * (NOUT * DOUT / 2) + o * (DOUT / 2) + dg];
                float p = u0 * vv.x + u1 * vv.y;
                p += __shfl_xor(p, 1);
                p += __shfl_xor(p, 2);
                p += __shfl_xor(p, 4);
                p += __shfl_xor(p, 8);          // full dot over d in 16-lane group
                if (dg == 0) lg[par][bb][o] = p;
                ustash[bb][t] = make_float2(u0, u1);
            }
            __syncthreads();                    // 1 barrier per nn
#pragma unroll
            for (int bb = 0; bb < BQ; ++bb) {
                // softmax over o=64; no max-sub needed (|logit| << 88)
                float e = __expf(lg[par][bb][lane]);
                float sm = e;
#pragma unroll
                for (int m = 1; m < 64; m <<= 1) sm += __shfl_xor(sm, m);
                const float cw = __shfl(e, o) / sm;
                const float2 u = ustash[bb][t];
                acc0[bb] += cw * u.x;
                acc1[bb] += cw * u.y;
            }
        }
    }

    const float scale = (PASS == 1) ? (1.0f / 64.0f) : 1.0f;
    if constexpr (ATOMIC) {
#pragma unroll
        for (int bb = 0; bb < BQ; ++bb) {
            float* dst = &s_out[((size_t)(bbase + bb) * NOUT + o) * DOUT + d0];
            atomicAdd(dst,     acc0[bb] * scale);
            atomicAdd(dst + 1, acc1[bb] * scale);
        }
    } else {
        // streaming coalesced partial store: part[(cg*4+quad)][bb][o][dg]
        float2* base = part + (size_t)(cg * 4 + quad) * PART_PER_BLK;
#pragma unroll
        for (int bb = 0; bb < BQ; ++bb)
            base[bb * (NOUT * DOUT / 2) + o * (DOUT / 2) + dg] =
                make_float2(acc0[bb] * scale, acc1[bb] * scale);
    }
}

// sum 128 chunk-partials per element, then squash per (b,o) row (16 lanes)
__global__ __launch_bounds__(256)
void reduce_squash(const float2* __restrict__ part, float* __restrict__ vout,
                   int accumulate)
{
    const int id = blockIdx.x * 256 + threadIdx.x;   // 0..32767
    const int dg = id & 15;
    const int o  = (id >> 4) & 63;
    const int b  = id >> 10;
    const int quad = b >> 3, bb = b & 7;
    const size_t base = (size_t)bb * (NOUT * DOUT / 2) + o * (DOUT / 2) + dg;

    float2 a0 = make_float2(0.f, 0.f), a1 = make_float2(0.f, 0.f);
    for (int cg = 0; cg < CG; cg += 2) {
        const float2 p0 = part[(size_t)(cg * 4 + quad) * PART_PER_BLK + base];
        const float2 p1 = part[(size_t)((cg + 1) * 4 + quad) * PART_PER_BLK + base];
        a0.x += p0.x; a0.y += p0.y;
        a1.x += p1.x; a1.y += p1.y;
    }
    const float sx = a0.x + a1.x, sy = a0.y + a1.y;

    float sq = sx * sx + sy * sy;
    sq += __shfl_xor(sq, 1);
    sq += __shfl_xor(sq, 2);
    sq += __shfl_xor(sq, 4);
    sq += __shfl_xor(sq, 8);        // row (b,o) = 16-lane group
    const float f = sq / ((1.0f + sq) * sqrtf(sq + 1e-8f));

    float2* vo = (float2*)vout;
    float2 r = make_float2(sx * f, sy * f);
    if (accumulate) {
        const float2 old = vo[id];
        r.x += old.x; r.y += old.y;
    }
    vo[id] = r;
}

// fallback squash for the atomic path
__global__ void squash_k(const float* __restrict__ s, float* __restrict__ vout,
                         int accumulate)
{
    const int idx = blockIdx.x * 256 + threadIdx.x;   // 65536 elements
    const float val = s[idx];
    float sq = val * val;
#pragma unroll
    for (int m = 1; m < 32; m <<= 1) sq += __shfl_xor(sq, m);
    const float f = sq / ((1.0f + sq) * sqrtf(sq + 1e-8f));
    const float v = val * f;
    if (accumulate) vout[idx] += v;
    else            vout[idx] = v;
}

extern "C" void kernel_launch(void* const* d_in, const int* in_sizes, int n_in,
                              void* d_out, int out_size, void* d_ws, size_t ws_size,
                              hipStream_t stream)
{
    (void)in_sizes; (void)n_in; (void)out_size;
    const float* x = (const float*)d_in[0];
    const float* W = (const float*)d_in[1];
    float* out = (float*)d_out;

    const size_t partBytes = (size_t)NBLK * PART_PER_BLK * sizeof(float2); // 32 MB
    const size_t vBytes    = (size_t)B_ * NOUT * DOUT * sizeof(float);     // 256 KB

    if (ws_size >= partBytes + vBytes) {
        // ---- partial-sum path (no global atomics)
        float2* part = (float2*)d_ws;
        float*  vA   = (float*)((char*)d_ws + partBytes);

        caps_pass<1, false><<<dim3(NBLK), dim3(TPB), 0, stream>>>(W, x, nullptr, nullptr, part);
        reduce_squash<<<dim3(128), dim3(256), 0, stream>>>(part, vA, 0);   // vA = v1

        caps_pass<2, false><<<dim3(NBLK), dim3(TPB), 0, stream>>>(W, x, vA, nullptr, part);
        reduce_squash<<<dim3(128), dim3(256), 0, stream>>>(part, vA, 1);   // vA = v1+v2

        caps_pass<2, false><<<dim3(NBLK), dim3(TPB), 0, stream>>>(W, x, vA, nullptr, part);
        reduce_squash<<<dim3(128), dim3(256), 0, stream>>>(part, out, 0);  // out = v3
    } else {
        // ---- atomic fallback (round-5 behavior)
        float* s  = (float*)d_ws;
        float* vA = s + B_ * NOUT * DOUT;
        const size_t sbytes = vBytes;

        hipMemsetAsync(s, 0, sbytes, stream);
        caps_pass<1, true><<<dim3(NBLK), dim3(TPB), 0, stream>>>(W, x, nullptr, s, nullptr);
        squash_k<<<dim3(256), dim3(256), 0, stream>>>(s, vA, 0);

        hipMemsetAsync(s, 0, sbytes, stream);
        caps_pass<2, true><<<dim3(NBLK), dim3(TPB), 0, stream>>>(W, x, vA, s, nullptr);
        squash_k<<<dim3(256), dim3(256), 0, stream>>>(s, vA, 1);

        hipMemsetAsync(s, 0, sbytes, stream);
        caps_pass<2, true><<<dim3(NBLK), dim3(TPB), 0, stream>>>(W, x, vA, s, nullptr);
        squash_k<<<dim3(256), dim3(256), 0, stream>>>(s, out, 0);
    }
}